// Round 8
// baseline (110.743 us; speedup 1.0000x reference)
//
#include <hip/hip_runtime.h>

typedef _Float16 f16;
typedef __attribute__((ext_vector_type(4))) _Float16 f16x4;
typedef __attribute__((ext_vector_type(8))) _Float16 f16x8;
typedef __attribute__((ext_vector_type(4))) float f32x4;

#define CEXP 0.18033688011112042f  /* 0.125 * log2(e) : folded into Q at GEMM epilogue */
#define QKB_LD 1056   /* 1024 + 32: L2 channel spread */

__device__ __forceinline__ void gload16(const f16* g, f16* l) {
    __builtin_amdgcn_global_load_lds((const __attribute__((address_space(1))) void*)g,
                                     (__attribute__((address_space(3))) void*)l, 16, 0, 0);
}

// ---------------- fp32 -> f16 convert (vectorized) ----------------
__global__ __launch_bounds__(256) void conv_f32_f16_k(const float* __restrict__ in,
                                                      f16* __restrict__ out) {
    int idx = (blockIdx.x * 256 + threadIdx.x) * 8;
    float4 a = *(const float4*)(in + idx);
    float4 b = *(const float4*)(in + idx + 4);
    f16x8 o;
    o[0] = (f16)a.x; o[1] = (f16)a.y; o[2] = (f16)a.z; o[3] = (f16)a.w;
    o[4] = (f16)b.x; o[5] = (f16)b.y; o[6] = (f16)b.z; o[7] = (f16)b.w;
    *(f16x8*)(out + idx) = o;
}

// ---- transpose + convert: out[(row_off+n)*ldo + k] = in[k*N + n] ----
__global__ __launch_bounds__(256) void transpose_conv_k(const float* __restrict__ in,
                                                        f16* __restrict__ out,
                                                        int N, int ldo, int row_off) {
    __shared__ float tile[32][33];
    int tx = threadIdx.x & 31, ty = threadIdx.x >> 5;  // 32 x 8
    int n0 = blockIdx.x * 32, k0 = blockIdx.y * 32;
#pragma unroll
    for (int j = 0; j < 4; j++)
        tile[ty + j * 8][tx] = in[(size_t)(k0 + ty + j * 8) * N + n0 + tx];
    __syncthreads();
#pragma unroll
    for (int j = 0; j < 4; j++)
        out[(size_t)(row_off + n0 + ty + j * 8) * ldo + k0 + tx] = (f16)tile[tx][ty + j * 8];
}

// ---------------- 128xBN f16 MFMA GEMM (m97 structure) ----------------
// MODE 0: f16 to Cqk (Q cols pre-scaled by CEXP); V written FRAGMENT-MAJOR to Cvt:
//   vtb2[pair][t][kg][dgp][lane=lga*16+lra][dh*4+e] so attn reads it coalesced.
// MODE 1: fp32 + bias to Cout.
template <int MODE, int BN>
__global__ __launch_bounds__(256) void gemm_k(
    const f16* __restrict__ A, const f16* __restrict__ Bt,
    f16* __restrict__ Cqk, f16* __restrict__ Cvt,
    float* __restrict__ Cout, const float* __restrict__ bias,
    int K, int NTILES) {
    __shared__ __align__(16) f16 As[128 * 64];
    __shared__ __align__(16) f16 Bs[BN * 64];
    constexpr int MI = (BN == 128) ? 4 : 2;
    int bid = blockIdx.x;
    int nt = bid % NTILES, mt = bid / NTILES;
    int m0 = mt * 128, n0 = nt * BN;
    int tid = threadIdx.x;
    int lane = tid & 63, w = tid >> 6;
    int rowBase = (BN == 128) ? (w >> 1) * 64 : w * 32;
    int colBase = (BN == 128) ? (w & 1) * 64 : 0;
    int lr = lane & 15, lg = lane >> 4;
    int rowL = lane >> 3;
    int colL = (lane & 7) * 8;
    int bRow0 = (BN == 128) ? w * 32 : w * 16;
    const f16* aSrc = A + (size_t)(m0 + w * 32 + rowL) * K + colL;
    const f16* bSrc = Bt + (size_t)(n0 + bRow0 + rowL) * K + colL;
    f32x4 acc[MI][4] = {};

    for (int k0 = 0; k0 < K; k0 += 64) {
#pragma unroll
        for (int j = 0; j < 4; j++)
            gload16(aSrc + k0 + (size_t)(j * 8) * K, &As[(w * 32 + j * 8) * 64]);
#pragma unroll
        for (int j = 0; j < (BN == 128 ? 4 : 2); j++)
            gload16(bSrc + k0 + (size_t)(j * 8) * K, &Bs[(bRow0 + j * 8) * 64]);
        __syncthreads();
#pragma unroll
        for (int ks = 0; ks < 2; ks++) {
            f16x8 af[MI], bf[4];
#pragma unroll
            for (int i = 0; i < MI; i++)
                af[i] = *(const f16x8*)(&As[(rowBase + i * 16 + lr) * 64 + ks * 32 + lg * 8]);
#pragma unroll
            for (int j = 0; j < 4; j++)
                bf[j] = *(const f16x8*)(&Bs[(colBase + j * 16 + lr) * 64 + ks * 32 + lg * 8]);
#pragma unroll
            for (int i = 0; i < MI; i++)
#pragma unroll
                for (int j = 0; j < 4; j++)
                    acc[i][j] = __builtin_amdgcn_mfma_f32_16x16x32_f16(af[i], bf[j], acc[i][j], 0, 0, 0);
        }
        __syncthreads();
    }

#pragma unroll
    for (int i = 0; i < MI; i++) {
#pragma unroll
        for (int j = 0; j < 4; j++) {
            int row = m0 + rowBase + i * 16 + lg * 4;
            int col = n0 + colBase + j * 16 + lr;
            if (MODE == 1) {
                float bv = bias[col];
#pragma unroll
                for (int r = 0; r < 4; r++)
                    Cout[(size_t)(row + r) * 1024 + col] = acc[i][j][r] + bv;
            } else {
                if (col < 1024) {
                    float sc = (col < 512) ? CEXP : 1.0f;
#pragma unroll
                    for (int r = 0; r < 4; r++)
                        Cqk[(size_t)(row + r) * QKB_LD + col] = (f16)(acc[i][j][r] * sc);
                } else {
                    // fragment-major V^T write (one f16x4 store, e = r)
                    int c = col - 1024;
                    int hh = c >> 6, d = c & 63;
                    int bb = row >> 11, n = row & 2047;
                    int pr = bb * 8 + hh;
                    int tt = n >> 6, kvl = n & 63;
                    int kg = kvl >> 4, lga = (kvl >> 2) & 3;
                    int dgp = d >> 5, dh = (d >> 4) & 1, lra = d & 15;
                    f16x4 ov;
#pragma unroll
                    for (int r = 0; r < 4; r++) ov[r] = (f16)acc[i][j][r];
                    size_t idx = ((((size_t)(pr * 32 + tt) * 4 + kg) * 2 + dgp) * 64
                                  + lga * 16 + lra) * 8 + dh * 4;
                    *(f16x4*)(Cvt + idx) = ov;
                }
            }
        }
    }
}

// ---------------- flash attention: register-direct, barrier-free, KV-split x2 ----------------
// 1024 blocks (pair x 64 qblks of 32 rows). Wave w: q-subtile (w&1, 16 rows),
// KV half (w>>1, 1024 kv). K read directly from qkb rows (16 full-line gather,
// 100% line use); V from fragment-major vtb2 (coalesced 1KB/instr). No LDS in
// the loop, no barriers, no waitcnt asm — plain loads, issue-early scheduling:
// V(t) at iter top, K(t+1) right after QK(t). Single LDS merge at the end.
// S^T = K*Q^T (zero-shuffle P); Q pre-scaled -> exp2 direct; defer-max vote.
__global__ __launch_bounds__(256, 3) void attn_k(const f16* __restrict__ qkb,
                                                 const f16* __restrict__ vt2,
                                                 f16* __restrict__ ao) {
    __shared__ float accS[4][64][16];
    __shared__ float lpS[4][64];
    __shared__ float mS[4][64];

    int bid = blockIdx.x;
    int xcd = bid & 7;
    int pair = xcd * 2 + ((bid >> 3) & 1);  // 2 pairs per XCD -> K/V L2-resident
    int qblk = bid >> 4;                    // 0..63
    int b = pair >> 3, h = pair & 7;
    int tid = threadIdx.x;
    int lane = tid & 63, w = tid >> 6;
    int lr = lane & 15, lg = lane >> 4;
    int qsub = w & 1, half = w >> 1;
    int q0 = qblk * 32 + qsub * 16;

    const f16* qb = qkb + (size_t)b * 2048 * QKB_LD + h * 64;
    const f16* kb = qb + 512;
    const f16* vbase = vt2 + ((size_t)pair * 32) * 4096 + lane * 8;

    // Q fragments (held for whole kernel; pre-scaled by CEXP)
    f16x8 qf0 = *(const f16x8*)(qb + (size_t)(q0 + lr) * QKB_LD + lg * 8);
    f16x8 qf1 = *(const f16x8*)(qb + (size_t)(q0 + lr) * QKB_LD + 32 + lg * 8);

    // K row-gather base: row kvBase+kg*16+lr, cols lg*8 (+32 for hi frag)
    const f16* krow = kb + (size_t)(half * 1024 + lr) * QKB_LD + lg * 8;

    // prologue: K(0) into registers
    f16x8 ka0[4], ka1[4];
#pragma unroll
    for (int kg = 0; kg < 4; kg++) {
        const f16* p = krow + (size_t)(kg * 16) * QKB_LD;
        ka0[kg] = *(const f16x8*)(p);
        ka1[kg] = *(const f16x8*)(p + 32);
    }

    f32x4 acc[4] = {};
    float m = -INFINITY, lp = 0.f;

    for (int t = 0; t < 16; t++) {
        // ---- V(t): issue coalesced loads at top (land under QK + softmax) ----
        const f16* vl = vbase + (size_t)(half * 16 + t) * 4096;
        f16x8 vv[8];
#pragma unroll
        for (int i = 0; i < 8; i++) vv[i] = *(const f16x8*)(vl + i * 512);

        // ---- QK(t): S^T tile [64 kv][16 q] ----
        f32x4 s[4];
        __builtin_amdgcn_s_setprio(1);
#pragma unroll
        for (int kg = 0; kg < 4; kg++) {
            f32x4 z = {};
            z = __builtin_amdgcn_mfma_f32_16x16x32_f16(ka0[kg], qf0, z, 0, 0, 0);
            s[kg] = __builtin_amdgcn_mfma_f32_16x16x32_f16(ka1[kg], qf1, z, 0, 0, 0);
        }
        __builtin_amdgcn_s_setprio(0);

        // ---- K(t+1): issue right after ka consumed (lands under softmax + PV) ----
        if (t < 15) {
            const f16* p2 = krow + (size_t)((t + 1) * 64) * QKB_LD;
#pragma unroll
            for (int kg = 0; kg < 4; kg++) {
                const f16* p = p2 + (size_t)(kg * 16) * QKB_LD;
                ka0[kg] = *(const f16x8*)(p);
                ka1[kg] = *(const f16x8*)(p + 32);
            }
        }

        // ---- softmax: lane-local defer-max vote, shuffle-free common path ----
        float x0 = fmaxf(fmaxf(s[0][0], s[0][1]), fmaxf(s[0][2], s[0][3]));
        float x1 = fmaxf(fmaxf(s[1][0], s[1][1]), fmaxf(s[1][2], s[1][3]));
        float x2 = fmaxf(fmaxf(s[2][0], s[2][1]), fmaxf(s[2][2], s[2][3]));
        float x3 = fmaxf(fmaxf(s[3][0], s[3][1]), fmaxf(s[3][2], s[3][3]));
        float ownmx = fmaxf(fmaxf(x0, x1), fmaxf(x2, x3));
        if (!__all(ownmx - m <= 8.f)) {
            float mx = fmaxf(ownmx, __shfl_xor(ownmx, 16, 64));
            mx = fmaxf(mx, __shfl_xor(mx, 32, 64));
            float mn = fmaxf(m, mx);
            float alpha = __builtin_amdgcn_exp2f(m - mn);
            m = mn;
            lp *= alpha;
#pragma unroll
            for (int dg = 0; dg < 4; dg++)
#pragma unroll
                for (int r = 0; r < 4; r++) acc[dg][r] *= alpha;
        }
        f16x4 pf[4];
#pragma unroll
        for (int kg = 0; kg < 4; kg++) {
            float p0 = __builtin_amdgcn_exp2f(s[kg][0] - m);
            float p1 = __builtin_amdgcn_exp2f(s[kg][1] - m);
            float p2 = __builtin_amdgcn_exp2f(s[kg][2] - m);
            float p3 = __builtin_amdgcn_exp2f(s[kg][3] - m);
            pf[kg][0] = (f16)p0; pf[kg][1] = (f16)p1;
            pf[kg][2] = (f16)p2; pf[kg][3] = (f16)p3;
            lp += (p0 + p1) + (p2 + p3);
        }

        // ---- PV (compiler waits vv here) ----
        __builtin_amdgcn_s_setprio(1);
#pragma unroll
        for (int kg = 0; kg < 4; kg++)
#pragma unroll
            for (int dgp = 0; dgp < 2; dgp++) {
                f16x8 vx = vv[kg * 2 + dgp];
                f16x4 vlo = __builtin_shufflevector(vx, vx, 0, 1, 2, 3);
                f16x4 vhi = __builtin_shufflevector(vx, vx, 4, 5, 6, 7);
                acc[dgp * 2]     = __builtin_amdgcn_mfma_f32_16x16x16f16(vlo, pf[kg], acc[dgp * 2], 0, 0, 0);
                acc[dgp * 2 + 1] = __builtin_amdgcn_mfma_f32_16x16x16f16(vhi, pf[kg], acc[dgp * 2 + 1], 0, 0, 0);
            }
        __builtin_amdgcn_s_setprio(0);
    }

    // ---- merge the two KV halves (one barrier, tiny LDS) ----
    lp += __shfl_xor(lp, 16, 64);
    lp += __shfl_xor(lp, 32, 64);   // per-q-row sum (uniform over lg)
#pragma unroll
    for (int dg = 0; dg < 4; dg++) *(f32x4*)&accS[w][lane][dg * 4] = acc[dg];
    lpS[w][lane] = lp;
    mS[w][lane] = m;
    __syncthreads();

    if (w < 2) {
        float mP = mS[w + 2][lane];
        float lpP = lpS[w + 2][lane];
        float M = fmaxf(m, mP);
        float a = __builtin_amdgcn_exp2f(m - M);
        float c = __builtin_amdgcn_exp2f(mP - M);
        float inv = 1.f / (lp * a + lpP * c);
#pragma unroll
        for (int dg = 0; dg < 4; dg++) {
            f32x4 oP = *(const f32x4*)&accS[w + 2][lane][dg * 4];
            f16x4 ov;
#pragma unroll
            for (int r = 0; r < 4; r++)
                ov[r] = (f16)((acc[dg][r] * a + oP[r] * c) * inv);
            *(f16x4*)(ao + (size_t)(b * 2048 + q0 + lr) * 512 + h * 64 + dg * 16 + lg * 4) = ov;
        }
    }
}

extern "C" void kernel_launch(void* const* d_in, const int* in_sizes, int n_in,
                              void* d_out, int out_size, void* d_ws, size_t ws_size,
                              hipStream_t stream) {
    const float* x   = (const float*)d_in[0];
    const float* Wq  = (const float*)d_in[1];
    const float* Wkv = (const float*)d_in[2];
    const float* Wo  = (const float*)d_in[3];
    const float* bo  = (const float*)d_in[4];
    float* out = (float*)d_out;

    f16* xb    = (f16*)d_ws;                  // [4096][1024]
    f16* wqkvT = xb + 4096 * 1024;            // [1536][1024]
    f16* woT   = wqkvT + 1536 * 1024;         // [1024][512]
    f16* qkb   = woT + 1024 * 512;            // [4096][QKB_LD]  (Q*CEXP | K)
    f16* vtb2  = qkb + 4096 * QKB_LD;         // [16][32][8][512] fragment-major V^T
    f16* ao    = vtb2 + 16 * 32 * 4096;       // [4096][512]

    conv_f32_f16_k<<<2048, 256, 0, stream>>>(x, xb);
    transpose_conv_k<<<dim3(16, 32), 256, 0, stream>>>(Wq, wqkvT, 512, 1024, 0);
    transpose_conv_k<<<dim3(32, 32), 256, 0, stream>>>(Wkv, wqkvT, 1024, 1024, 512);
    transpose_conv_k<<<dim3(32, 16), 256, 0, stream>>>(Wo, woT, 1024, 512, 0);

    gemm_k<0, 64><<<32 * 24, 256, 0, stream>>>(xb, wqkvT, qkb, vtb2, nullptr, nullptr, 1024, 24);
    attn_k<<<1024, 256, 0, stream>>>(qkb, vtb2, ao);
    gemm_k<1, 128><<<32 * 8, 256, 0, stream>>>(ao, woT, nullptr, nullptr, out, bo, 512, 8);
}

// Round 9
// 90.083 us; speedup vs baseline: 1.2294x; 1.2294x over previous
//
#include <hip/hip_runtime.h>

typedef _Float16 f16;
typedef __attribute__((ext_vector_type(4))) _Float16 f16x4;
typedef __attribute__((ext_vector_type(8))) _Float16 f16x8;
typedef __attribute__((ext_vector_type(4))) float f32x4;

#define CEXP 0.18033688011112042f  /* 0.125 * log2(e) : folded into Q at GEMM epilogue */
#define QKB_LD 1056   /* 1024 + 32: L2 channel spread */

__device__ __forceinline__ void gload16(const f16* g, f16* l) {
    __builtin_amdgcn_global_load_lds((const __attribute__((address_space(1))) void*)g,
                                     (__attribute__((address_space(3))) void*)l, 16, 0, 0);
}

// ---------------- fp32 -> f16 convert (vectorized) ----------------
__global__ __launch_bounds__(256) void conv_f32_f16_k(const float* __restrict__ in,
                                                      f16* __restrict__ out) {
    int idx = (blockIdx.x * 256 + threadIdx.x) * 8;
    float4 a = *(const float4*)(in + idx);
    float4 b = *(const float4*)(in + idx + 4);
    f16x8 o;
    o[0] = (f16)a.x; o[1] = (f16)a.y; o[2] = (f16)a.z; o[3] = (f16)a.w;
    o[4] = (f16)b.x; o[5] = (f16)b.y; o[6] = (f16)b.z; o[7] = (f16)b.w;
    *(f16x8*)(out + idx) = o;
}

// ---- transpose + convert: out[(row_off+n)*ldo + k] = in[k*N + n] ----
__global__ __launch_bounds__(256) void transpose_conv_k(const float* __restrict__ in,
                                                        f16* __restrict__ out,
                                                        int N, int ldo, int row_off) {
    __shared__ float tile[32][33];
    int tx = threadIdx.x & 31, ty = threadIdx.x >> 5;  // 32 x 8
    int n0 = blockIdx.x * 32, k0 = blockIdx.y * 32;
#pragma unroll
    for (int j = 0; j < 4; j++)
        tile[ty + j * 8][tx] = in[(size_t)(k0 + ty + j * 8) * N + n0 + tx];
    __syncthreads();
#pragma unroll
    for (int j = 0; j < 4; j++)
        out[(size_t)(row_off + n0 + ty + j * 8) * ldo + k0 + tx] = (f16)tile[tx][ty + j * 8];
}

// ---------------- 128xBN f16 MFMA GEMM (m97 structure) ----------------
// MODE 0: f16 to Cqk (Q cols pre-scaled by CEXP); V written FRAGMENT-MAJOR to Cvt:
//   vtb2[pair][t][kg][dgp][lane=lga*16+lra][dh*4+e] so attn stages it coalesced.
// MODE 1: fp32 + bias to Cout.
template <int MODE, int BN>
__global__ __launch_bounds__(256) void gemm_k(
    const f16* __restrict__ A, const f16* __restrict__ Bt,
    f16* __restrict__ Cqk, f16* __restrict__ Cvt,
    float* __restrict__ Cout, const float* __restrict__ bias,
    int K, int NTILES) {
    __shared__ __align__(16) f16 As[128 * 64];
    __shared__ __align__(16) f16 Bs[BN * 64];
    constexpr int MI = (BN == 128) ? 4 : 2;
    int bid = blockIdx.x;
    int nt = bid % NTILES, mt = bid / NTILES;
    int m0 = mt * 128, n0 = nt * BN;
    int tid = threadIdx.x;
    int lane = tid & 63, w = tid >> 6;
    int rowBase = (BN == 128) ? (w >> 1) * 64 : w * 32;
    int colBase = (BN == 128) ? (w & 1) * 64 : 0;
    int lr = lane & 15, lg = lane >> 4;
    int rowL = lane >> 3;
    int colL = (lane & 7) * 8;
    int bRow0 = (BN == 128) ? w * 32 : w * 16;
    const f16* aSrc = A + (size_t)(m0 + w * 32 + rowL) * K + colL;
    const f16* bSrc = Bt + (size_t)(n0 + bRow0 + rowL) * K + colL;
    f32x4 acc[MI][4] = {};

    for (int k0 = 0; k0 < K; k0 += 64) {
#pragma unroll
        for (int j = 0; j < 4; j++)
            gload16(aSrc + k0 + (size_t)(j * 8) * K, &As[(w * 32 + j * 8) * 64]);
#pragma unroll
        for (int j = 0; j < (BN == 128 ? 4 : 2); j++)
            gload16(bSrc + k0 + (size_t)(j * 8) * K, &Bs[(bRow0 + j * 8) * 64]);
        __syncthreads();
#pragma unroll
        for (int ks = 0; ks < 2; ks++) {
            f16x8 af[MI], bf[4];
#pragma unroll
            for (int i = 0; i < MI; i++)
                af[i] = *(const f16x8*)(&As[(rowBase + i * 16 + lr) * 64 + ks * 32 + lg * 8]);
#pragma unroll
            for (int j = 0; j < 4; j++)
                bf[j] = *(const f16x8*)(&Bs[(colBase + j * 16 + lr) * 64 + ks * 32 + lg * 8]);
#pragma unroll
            for (int i = 0; i < MI; i++)
#pragma unroll
                for (int j = 0; j < 4; j++)
                    acc[i][j] = __builtin_amdgcn_mfma_f32_16x16x32_f16(af[i], bf[j], acc[i][j], 0, 0, 0);
        }
        __syncthreads();
    }

#pragma unroll
    for (int i = 0; i < MI; i++) {
#pragma unroll
        for (int j = 0; j < 4; j++) {
            int row = m0 + rowBase + i * 16 + lg * 4;
            int col = n0 + colBase + j * 16 + lr;
            if (MODE == 1) {
                float bv = bias[col];
#pragma unroll
                for (int r = 0; r < 4; r++)
                    Cout[(size_t)(row + r) * 1024 + col] = acc[i][j][r] + bv;
            } else {
                if (col < 1024) {
                    float sc = (col < 512) ? CEXP : 1.0f;
#pragma unroll
                    for (int r = 0; r < 4; r++)
                        Cqk[(size_t)(row + r) * QKB_LD + col] = (f16)(acc[i][j][r] * sc);
                } else {
                    // fragment-major V^T write (one f16x4 store, e = r)
                    int c = col - 1024;
                    int hh = c >> 6, d = c & 63;
                    int bb = row >> 11, n = row & 2047;
                    int pr = bb * 8 + hh;
                    int tt = n >> 6, kvl = n & 63;
                    int kg = kvl >> 4, lga = (kvl >> 2) & 3;
                    int dgp = d >> 5, dh = (d >> 4) & 1, lra = d & 15;
                    f16x4 ov;
#pragma unroll
                    for (int r = 0; r < 4; r++) ov[r] = (f16)acc[i][j][r];
                    size_t idx = ((((size_t)(pr * 32 + tt) * 4 + kg) * 2 + dgp) * 64
                                  + lga * 16 + lra) * 8 + dh * 4;
                    *(f16x4*)(Cvt + idx) = ov;
                }
            }
        }
    }
}

// ---------------- flash attention: 8 waves, in-block KV-split x2 ----------------
// 512 blocks x 512 threads. Waves 0-3: KV [0,1024); waves 4-7: KV [1024,2048);
// each wave 16 q-rows of the same 64-row q-block. Per half: K 3 LDS buffers
// (XOR-swizzled both sides), V 2 buffers (fragment-major, conflict-free b128).
// Stage K(t+2)/V(t+1) at iter top; plain __syncthreads per iter (loads get a
// full body to land). QK(t+1) prefetch overlaps softmax(t). End: merge halves
// through reused K-LDS. 80 KB LDS -> 2 blocks/CU -> 4 waves/SIMD.
__global__ __launch_bounds__(512, 4) void attn_k(const f16* __restrict__ qkb,
                                                 const f16* __restrict__ vt2,
                                                 f16* __restrict__ ao) {
    __shared__ __align__(16) f16 Ks[2][3 * 4096];   // 48 KB
    __shared__ __align__(16) f16 Vs[2][2 * 4096];   // 32 KB

    int bid = blockIdx.x;
    int xcd = bid & 7;
    int pair = xcd * 2 + ((bid >> 3) & 1);  // pin each pair's K/V to one XCD L2
    int qblk = bid >> 4;                    // 0..31
    int b = pair >> 3, h = pair & 7;
    int tid = threadIdx.x;
    int lane = tid & 63, w = tid >> 6;
    int half = w >> 2, wl = w & 3;
    int lr = lane & 15, lg = lane >> 4;
    int q0 = qblk * 64 + wl * 16;

    const f16* qb = qkb + (size_t)b * 2048 * QKB_LD + h * 64;
    const f16* kb = qb + 512;

    f16x8 qf0 = *(const f16x8*)(qb + (size_t)(q0 + lr) * QKB_LD + lg * 8);
    f16x8 qf1 = *(const f16x8*)(qb + (size_t)(q0 + lr) * QKB_LD + 32 + lg * 8);

    // K staging: inverse-swizzled source col, linear LDS dest
    int srcCol = (((lane & 7) ^ (lane >> 3)) << 3);
    int rowL = lane >> 3;
    const f16* ksrc = kb + (size_t)(half * 1024 + wl * 16 + rowL) * QKB_LD + srcCol;
    // V staging: fragment-major, fully linear
    const f16* vsrc = vt2 + ((size_t)(pair * 32 + half * 16) * 8 + 2 * wl) * 512 + lane * 8;

    auto stageK = [&](int buf, int tt) {  // tt: tile index within half (0..15)
        f16* dst = &Ks[half][buf * 4096 + (wl * 16) * 64];
        gload16(ksrc + (size_t)(tt * 64) * QKB_LD, dst);
        gload16(ksrc + (size_t)(tt * 64 + 8) * QKB_LD, dst + 8 * 64);
    };
    auto stageV = [&](int buf, int tt) {
        const f16* s = vsrc + (size_t)tt * 4096;
        f16* dst = &Vs[half][buf * 4096 + (2 * wl) * 512];
        gload16(s, dst);
        gload16(s + 512, dst + 512);
    };

    stageK(0, 0); stageV(0, 0); stageK(1, 1);
    __syncthreads();

    int kOffA = (lg * 8) ^ ((lr & 7) << 3);

    f32x4 acc[4] = {};
    float m = -INFINITY, lp = 0.f;
    f32x4 sA[4], sB[4];

    // QK(0) -> sA
    {
        __builtin_amdgcn_s_setprio(1);
#pragma unroll
        for (int kg = 0; kg < 4; kg++) {
            const f16* krow = &Ks[half][(kg * 16 + lr) * 64];
            f16x8 ka0 = *(const f16x8*)(krow + kOffA);
            f16x8 ka1 = *(const f16x8*)(krow + (kOffA ^ 32));
            f32x4 z = {};
            z = __builtin_amdgcn_mfma_f32_16x16x32_f16(ka0, qf0, z, 0, 0, 0);
            sA[kg] = __builtin_amdgcn_mfma_f32_16x16x32_f16(ka1, qf1, z, 0, 0, 0);
        }
        __builtin_amdgcn_s_setprio(0);
    }

    auto body = [&](f32x4 (&sCur)[4], f32x4 (&sNxt)[4], int t) {
        // A. stage K(t+2), V(t+1): issued at top, needed >= one full body later
        if (t <= 13) stageK((t + 2) % 3, t + 2);
        if (t <= 14) stageV((t + 1) & 1, t + 1);

        // B. QK(t+1) from landed K[(t+1)%3] — MFMA fills under softmax VALU
        if (t < 15) {
            const f16* kbuf = &Ks[half][((t + 1) % 3) * 4096];
            __builtin_amdgcn_s_setprio(1);
#pragma unroll
            for (int kg = 0; kg < 4; kg++) {
                const f16* krow = kbuf + (kg * 16 + lr) * 64;
                f16x8 ka0 = *(const f16x8*)(krow + kOffA);
                f16x8 ka1 = *(const f16x8*)(krow + (kOffA ^ 32));
                f32x4 z = {};
                z = __builtin_amdgcn_mfma_f32_16x16x32_f16(ka0, qf0, z, 0, 0, 0);
                sNxt[kg] = __builtin_amdgcn_mfma_f32_16x16x32_f16(ka1, qf1, z, 0, 0, 0);
            }
            __builtin_amdgcn_s_setprio(0);
        }

        // C. softmax(sCur): lane-local defer-max vote, shuffle-free common path
        float x0 = fmaxf(fmaxf(sCur[0][0], sCur[0][1]), fmaxf(sCur[0][2], sCur[0][3]));
        float x1 = fmaxf(fmaxf(sCur[1][0], sCur[1][1]), fmaxf(sCur[1][2], sCur[1][3]));
        float x2 = fmaxf(fmaxf(sCur[2][0], sCur[2][1]), fmaxf(sCur[2][2], sCur[2][3]));
        float x3 = fmaxf(fmaxf(sCur[3][0], sCur[3][1]), fmaxf(sCur[3][2], sCur[3][3]));
        float ownmx = fmaxf(fmaxf(x0, x1), fmaxf(x2, x3));
        if (!__all(ownmx - m <= 8.f)) {
            float mx = fmaxf(ownmx, __shfl_xor(ownmx, 16, 64));
            mx = fmaxf(mx, __shfl_xor(mx, 32, 64));
            float mn = fmaxf(m, mx);
            float alpha = __builtin_amdgcn_exp2f(m - mn);
            m = mn;
            lp *= alpha;
#pragma unroll
            for (int dg = 0; dg < 4; dg++)
#pragma unroll
                for (int r = 0; r < 4; r++) acc[dg][r] *= alpha;
        }
        f16x4 pf[4];
#pragma unroll
        for (int kg = 0; kg < 4; kg++) {
            float p0 = __builtin_amdgcn_exp2f(sCur[kg][0] - m);
            float p1 = __builtin_amdgcn_exp2f(sCur[kg][1] - m);
            float p2 = __builtin_amdgcn_exp2f(sCur[kg][2] - m);
            float p3 = __builtin_amdgcn_exp2f(sCur[kg][3] - m);
            pf[kg][0] = (f16)p0; pf[kg][1] = (f16)p1;
            pf[kg][2] = (f16)p2; pf[kg][3] = (f16)p3;
            lp += (p0 + p1) + (p2 + p3);
        }

        // D. PV: conflict-free b128, one vaddr + imm offsets
        const f16* vl = &Vs[half][(t & 1) * 4096] + lane * 8;
        __builtin_amdgcn_s_setprio(1);
#pragma unroll
        for (int kg = 0; kg < 4; kg++)
#pragma unroll
            for (int dgp = 0; dgp < 2; dgp++) {
                f16x8 vv = *(const f16x8*)(vl + (kg * 2 + dgp) * 512);
                f16x4 vlo = __builtin_shufflevector(vv, vv, 0, 1, 2, 3);
                f16x4 vhi = __builtin_shufflevector(vv, vv, 4, 5, 6, 7);
                acc[dgp * 2]     = __builtin_amdgcn_mfma_f32_16x16x16f16(vlo, pf[kg], acc[dgp * 2], 0, 0, 0);
                acc[dgp * 2 + 1] = __builtin_amdgcn_mfma_f32_16x16x16f16(vhi, pf[kg], acc[dgp * 2 + 1], 0, 0, 0);
            }
        __builtin_amdgcn_s_setprio(0);

        // E. drain + barrier (loads issued at top: latency fully covered)
        if (t < 15) __syncthreads();
    };

    for (int u = 0; u < 8; u++) {
        body(sA, sB, 2 * u);
        body(sB, sA, 2 * u + 1);
    }

    // ---- merge the two KV halves through reused K-LDS ----
    lp += __shfl_xor(lp, 16, 64);
    lp += __shfl_xor(lp, 32, 64);   // per-q-row sum (uniform over lg)
    __syncthreads();                // all PV reads done; Ks reusable
    float* mO = (float*)&Ks[0][0];          // [4][64][16]
    float* mL = mO + 4 * 64 * 16;           // [4][64]
    float* mM = mL + 4 * 64;                // [4][64]
    if (half == 1) {
#pragma unroll
        for (int dg = 0; dg < 4; dg++)
            *(f32x4*)&mO[(wl * 64 + lane) * 16 + dg * 4] = acc[dg];
        mL[wl * 64 + lane] = lp;
        mM[wl * 64 + lane] = m;
    }
    __syncthreads();
    if (half == 0) {
        float mP = mM[wl * 64 + lane];
        float lpP = mL[wl * 64 + lane];
        float M = fmaxf(m, mP);
        float a = __builtin_amdgcn_exp2f(m - M);
        float c = __builtin_amdgcn_exp2f(mP - M);
        float inv = 1.f / (lp * a + lpP * c);
#pragma unroll
        for (int dg = 0; dg < 4; dg++) {
            f32x4 oP = *(const f32x4*)&mO[(wl * 64 + lane) * 16 + dg * 4];
            f16x4 ov;
#pragma unroll
            for (int r = 0; r < 4; r++)
                ov[r] = (f16)((acc[dg][r] * a + oP[r] * c) * inv);
            *(f16x4*)(ao + (size_t)(b * 2048 + q0 + lr) * 512 + h * 64 + dg * 16 + lg * 4) = ov;
        }
    }
}

extern "C" void kernel_launch(void* const* d_in, const int* in_sizes, int n_in,
                              void* d_out, int out_size, void* d_ws, size_t ws_size,
                              hipStream_t stream) {
    const float* x   = (const float*)d_in[0];
    const float* Wq  = (const float*)d_in[1];
    const float* Wkv = (const float*)d_in[2];
    const float* Wo  = (const float*)d_in[3];
    const float* bo  = (const float*)d_in[4];
    float* out = (float*)d_out;

    f16* xb    = (f16*)d_ws;                  // [4096][1024]
    f16* wqkvT = xb + 4096 * 1024;            // [1536][1024]
    f16* woT   = wqkvT + 1536 * 1024;         // [1024][512]
    f16* qkb   = woT + 1024 * 512;            // [4096][QKB_LD]  (Q*CEXP | K)
    f16* vtb2  = qkb + 4096 * QKB_LD;         // [16][32][8][512] fragment-major V^T
    f16* ao    = vtb2 + 16 * 32 * 4096;       // [4096][512]

    conv_f32_f16_k<<<2048, 256, 0, stream>>>(x, xb);
    transpose_conv_k<<<dim3(16, 32), 256, 0, stream>>>(Wq, wqkvT, 512, 1024, 0);
    transpose_conv_k<<<dim3(32, 32), 256, 0, stream>>>(Wkv, wqkvT, 1024, 1024, 512);
    transpose_conv_k<<<dim3(32, 16), 256, 0, stream>>>(Wo, woT, 1024, 512, 0);

    gemm_k<0, 64><<<32 * 24, 256, 0, stream>>>(xb, wqkvT, qkb, vtb2, nullptr, nullptr, 1024, 24);
    attn_k<<<512, 512, 0, stream>>>(qkb, vtb2, ao);
    gemm_k<1, 128><<<32 * 8, 256, 0, stream>>>(ao, woT, nullptr, nullptr, out, bo, 512, 8);
}